// Round 19
// baseline (161.135 us; speedup 1.0000x reference)
//
#include <hip/hip_runtime.h>
#include <hip/hip_bf16.h>

#define NN 10000
#define KK 32
#define HH 128
#define TFH 32      // T_F/2
#define RFE 32
#define OUTF 64
#define START_T 0.25f
#define END_T 0.75f
#define ATTN_NORM 0.25f
#define T_NORM 0.17677669529663687f   // sqrt(1/32)
#define LN_EPS 1e-5f
#define MT 64

typedef __attribute__((ext_vector_type(4))) float f32x4;
typedef __attribute__((ext_vector_type(8))) short bf16x8;

__device__ __forceinline__ ushort f2bf(float x){
  __hip_bfloat16 b = __float2bfloat16(x);
  return *(ushort*)&b;
}
__device__ __forceinline__ float bf2f(ushort u){
  __hip_bfloat16 b = *(__hip_bfloat16*)&u;
  return __bfloat162float(b);
}

__device__ __forceinline__ float groupsum32(float v){
  v += __shfl_xor(v, 16, 32);
  v += __shfl_xor(v, 8, 32);
  v += __shfl_xor(v, 4, 32);
  v += __shfl_xor(v, 2, 32);
  v += __shfl_xor(v, 1, 32);
  return v;
}

__device__ __forceinline__ float wavesum64(float v){
  v += __shfl_xor(v, 32, 64);
  v += __shfl_xor(v, 16, 64);
  v += __shfl_xor(v, 8, 64);
  v += __shfl_xor(v, 4, 64);
  v += __shfl_xor(v, 2, 64);
  v += __shfl_xor(v, 1, 64);
  return v;
}

// ---------- one-time weight transposes to bf16 (all weights incl. WcT) ----------
__global__ __launch_bounds__(256) void k_prep_wT(const float* __restrict__ Wp, const float* __restrict__ Wkqv,
    const float* __restrict__ W1, const float* __restrict__ W2, const float* __restrict__ Wo,
    const float* __restrict__ Wtime, const float* __restrict__ Wedge,
    ushort* __restrict__ WpT, ushort* __restrict__ WkqvT, ushort* __restrict__ W1T,
    ushort* __restrict__ W2T, ushort* __restrict__ WoT, ushort* __restrict__ WcT){
  int id = blockIdx.x*256 + threadIdx.x;
  if (id < 16384){ int n=id>>7, k=id&127; WpT[id]=f2bf(Wp[k*HH+n]); return; }
  id -= 16384;
  if (id < 49152){ int n=id>>7, k=id&127; WkqvT[id]=f2bf(Wkqv[k*384+n]); return; }
  id -= 49152;
  if (id < 32768){ int n=id>>8, k=id&255; W1T[id]=f2bf(W1[k*HH+n]); return; }
  id -= 32768;
  if (id < 16384){ int n=id>>7, k=id&127; W2T[id]=f2bf(W2[k*HH+n]); return; }
  id -= 16384;
  if (id < 8192){ int n=id>>7, k=id&127; WoT[id]=f2bf(Wo[k*OUTF+n]); return; }
  id -= 8192;
  if (id < 24576){
    const int c = id/96, r = id%96;
    const int cc = (c < 128) ? c : (c + 128);
    const float v = (r < 64) ? Wtime[r*384 + cc] : Wedge[(r-64)*384 + cc];
    WcT[c*96 + r] = f2bf(v);
  }
}

#define LDA1 136   // 128+8 pad (ushorts)
#define LDA 104    // 96+8 pad (ushorts)
#define LDKV 264   // 256+8 pad (ushorts)
#define LDH 132    // 128+4 pad (floats)

// ---------- merged: proj (blocks [0,625)) | 2-node prep_node (blocks [625,5625)) ----------
__global__ __launch_bounds__(256) void k_node_proj(
    const float* __restrict__ X, const ushort* __restrict__ WpT, const float* __restrict__ bp,
    float* __restrict__ Y,
    const float* __restrict__ times, const int* __restrict__ nbrs,
    const float* __restrict__ Wt, const float* __restrict__ bt, const float* __restrict__ Wtime,
    float* __restrict__ tqq, float* __restrict__ tmaxb,
    int* __restrict__ cntb, uint* __restrict__ vmaskb, int* __restrict__ nbrC){
  __shared__ ushort As[16*LDA1];
  __shared__ float temb2[2][2*TFH];
  __shared__ float tmax_sh[2];
  const int tid = threadIdx.x;
  if (blockIdx.x < NN/16){
    const int n0 = blockIdx.x*16;
    #pragma unroll
    for (int p=0;p<2;++p){
      const int idx = tid + p*256;
      const int row = idx>>5, c4 = (idx&31)*4;
      const float4 v = *(const float4*)&X[(size_t)(n0+row)*HH + c4];
      *(ushort4*)&As[row*LDA1 + c4] = make_ushort4(f2bf(v.x), f2bf(v.y), f2bf(v.z), f2bf(v.w));
    }
    __syncthreads();
    const int w = tid>>6, lane = tid&63;
    const int lr = lane&15, lk8 = (lane>>4)*8, rbase = (lane>>4)*4;
    bf16x8 a[4];
    #pragma unroll
    for (int kk=0;kk<4;kk++) a[kk] = *(const bf16x8*)&As[lr*LDA1 + kk*32 + lk8];
    f32x4 acc[2];
    #pragma unroll
    for (int nt=0;nt<2;nt++) acc[nt] = (f32x4){0.f,0.f,0.f,0.f};
    #pragma unroll
    for (int nt=0;nt<2;nt++){
      const int n = w*2 + nt;
      #pragma unroll
      for (int kk=0;kk<4;kk++){
        bf16x8 b = *(const bf16x8*)&WpT[(n*16+lr)*HH + kk*32 + lk8];
        acc[nt] = __builtin_amdgcn_mfma_f32_16x16x32_bf16(a[kk], b, acc[nt],0,0,0);
      }
    }
    #pragma unroll
    for (int nt=0;nt<2;nt++){
      const int c = (w*2+nt)*16 + lr;
      const float bj = bp[c];
      #pragma unroll
      for (int r=0;r<4;r++)
        Y[(size_t)(n0 + rbase + r)*HH + c] = fmaxf(acc[nt][r] + bj, 0.f);
    }
  } else {
    const int node0 = (blockIdx.x - NN/16)*2;
    if (tid < MT){
      const int i = tid>>5, k = tid&31;
      const int node = node0 + i;
      const float t = times[node*KK + k];
      const bool valid = (t >= START_T) && (t < END_T);
      float val = valid ? t : START_T;
      #pragma unroll
      for (int off=16; off; off>>=1) val = fmaxf(val, __shfl_xor(val, off, 32));
      const unsigned long long bal = __ballot(valid);
      const uint vm = (uint)(bal >> (i*32));
      if (valid){
        const int slot = __popc(vm & ((1u<<k)-1));
        nbrC[node*KK + slot] = nbrs[node*KK + k];
      }
      if (k==0){ cntb[node] = __popc(vm); vmaskb[node] = vm; tmaxb[node] = val; tmax_sh[i] = val; }
    }
    __syncthreads();
    if (tid < MT){
      const int i = tid>>5, f = tid&31;
      const float hh = fmaf(tmax_sh[i] - START_T, Wt[f], bt[f]);
      temb2[i][2*f]   = __sinf(hh)*T_NORM;
      temb2[i][2*f+1] = __cosf(hh)*T_NORM;
    }
    __syncthreads();
    {
      const int i = tid>>7, jj = tid&127;
      float acc = 0.f;
      #pragma unroll
      for (int f=0; f<2*TFH; f++) acc = fmaf(temb2[i][f], Wtime[f*384 + HH + jj], acc);
      tqq[(size_t)(node0+i)*HH + jj] = acc;
    }
  }
}

// ---------- merged: prep_kv4 (blocks [0,5000)) | layer-0 ln_kqv (blocks [5000,5625)) ----------
// prep branch: register-dt + early rels issue (R16). Prep first so the long pole starts at t=0.
__global__ __launch_bounds__(256) void k_kv0_ln0(
    const float* __restrict__ times, const float* __restrict__ rels, const float* __restrict__ tmaxb,
    const float* __restrict__ Wt, const float* __restrict__ bt, const ushort* __restrict__ WcT,
    const uint* __restrict__ vmaskb, uint4* __restrict__ kvout,
    const float* __restrict__ Hin, const ushort* __restrict__ WkqvT,
    const float* __restrict__ g1, const float* __restrict__ b1, const float* __restrict__ tqq,
    float* __restrict__ XN, ushort* __restrict__ xnb,
    float* __restrict__ Qf, ushort* __restrict__ KVb){
  __shared__ ushort smem[MT*LDKV];
  const int tid = threadIdx.x;
  if (blockIdx.x >= NN/2){
    ushort* As = smem;
    const int n0 = (blockIdx.x - NN/2)*16;
    const int grp = tid>>5, gl = tid&31;
    {
      const float4 gv = *(const float4*)&g1[gl*4];
      const float4 bv = *(const float4*)&b1[gl*4];
      #pragma unroll
      for (int rr=0; rr<2; ++rr){
        const int row = grp + rr*8;
        const int node = n0 + row;
        float4 hv = *(const float4*)&Hin[(size_t)node*HH + gl*4];
        float s = hv.x+hv.y+hv.z+hv.w;
        s = groupsum32(s);
        const float mean = s*(1.f/HH);
        const float dx=hv.x-mean, dy=hv.y-mean, dz=hv.z-mean, dw=hv.w-mean;
        float vs = dx*dx+dy*dy+dz*dz+dw*dw;
        vs = groupsum32(vs);
        const float rstd = rsqrtf(vs*(1.f/HH)+LN_EPS);
        const float x0=dx*rstd*gv.x+bv.x, x1=dy*rstd*gv.y+bv.y, x2=dz*rstd*gv.z+bv.z, x3=dw*rstd*gv.w+bv.w;
        ushort4 pk = make_ushort4(f2bf(x0), f2bf(x1), f2bf(x2), f2bf(x3));
        *(ushort4*)&As[row*LDA1 + gl*4] = pk;
        *(float4*)&XN[(size_t)node*HH + gl*4] = make_float4(x0,x1,x2,x3);
        *(ushort4*)&xnb[(size_t)node*HH + gl*4] = pk;
      }
    }
    __syncthreads();
    const int w = tid>>6, lane = tid&63;
    const int lr = lane&15, lk8 = (lane>>4)*8, rbase = (lane>>4)*4;
    bf16x8 a[4];
    #pragma unroll
    for (int kk=0;kk<4;kk++) a[kk] = *(const bf16x8*)&As[lr*LDA1 + kk*32 + lk8];
    f32x4 acc[6];
    #pragma unroll
    for (int nt=0;nt<6;nt++) acc[nt] = (f32x4){0.f,0.f,0.f,0.f};
    #pragma unroll
    for (int nt=0;nt<6;nt++){
      const int n = w*6 + nt;
      #pragma unroll
      for (int kk=0;kk<4;kk++){
        bf16x8 b = *(const bf16x8*)&WkqvT[(n*16+lr)*HH + kk*32 + lk8];
        acc[nt] = __builtin_amdgcn_mfma_f32_16x16x32_bf16(a[kk], b, acc[nt],0,0,0);
      }
    }
    #pragma unroll
    for (int nt=0;nt<6;nt++){
      const int c = (w*6+nt)*16 + lr;
      #pragma unroll
      for (int r=0;r<4;r++){
        const int node = n0 + rbase + r;
        const float v = acc[nt][r];
        if (c < HH)           KVb[(size_t)node*256 + 2*c] = f2bf(v);
        else if (c < 2*HH)    Qf[(size_t)node*HH + (c-HH)] = v + tqq[(size_t)node*HH + (c-HH)];
        else                  KVb[(size_t)node*256 + 2*(c-2*HH) + 1] = f2bf(v);
      }
    }
  } else {
    ushort* Fa = smem;
    ushort* kvs = smem;
    const int node0 = blockIdx.x*2;
    // early independent loads: rels (HBM-latency hidden under sincos), tmax, vmask
    float4 rv[2];
    int relp[2], relseg[2];
    #pragma unroll
    for (int s0=0; s0<2; ++s0){
      const int i = tid + s0*256;
      relp[s0] = i>>3; relseg[s0] = i&7;
      rv[s0] = *(const float4*)&rels[((size_t)node0*KK + relp[s0])*RFE + relseg[s0]*4];
    }
    const float tmax0 = tmaxb[node0], tmax1 = tmaxb[node0+1];
    const uint vm0 = vmaskb[node0], vm1 = vmaskb[node0+1];
    // Fa sincos: f = tid&31 constant per thread; dt computed in registers (no dt_sh, no barrier)
    {
      const int f = tid&31;
      const float wtf = Wt[f], btf = bt[f];
      #pragma unroll
      for (int s0=0; s0<8; ++s0){
        const int p = (tid>>5) + 8*s0;
        const float tv = times[node0*KK + p];           // broadcast within 32-thread group
        const float dt = ((p < 32) ? tmax0 : tmax1) - tv;
        const float hh = fmaf(dt, wtf, btf);
        ushort2 pk;
        pk.x = f2bf(__sinf(hh)*T_NORM);
        pk.y = f2bf(__cosf(hh)*T_NORM);
        *(ushort2*)&Fa[p*LDA + 2*f] = pk;
      }
    }
    #pragma unroll
    for (int s0=0; s0<2; ++s0){
      ushort4 w2; w2.x=f2bf(rv[s0].x); w2.y=f2bf(rv[s0].y); w2.z=f2bf(rv[s0].z); w2.w=f2bf(rv[s0].w);
      *(ushort4*)&Fa[relp[s0]*LDA + 64 + relseg[s0]*4] = w2;
    }
    __syncthreads();
    const int wave = tid>>6, lane = tid&63;
    const int lr = lane&15, lk = (lane>>4)*8;
    f32x4 acc[4][4];
    #pragma unroll
    for (int m=0;m<4;m++)
      #pragma unroll
      for (int n=0;n<4;n++) acc[m][n] = (f32x4){0.f,0.f,0.f,0.f};
    #pragma unroll
    for (int kk=0; kk<3; ++kk){
      const int k0 = kk*32;
      bf16x8 a[4], b[4];
      #pragma unroll
      for (int m=0;m<4;m++) a[m] = *(const bf16x8*)&Fa[(m*16 + lr)*LDA + k0 + lk];
      #pragma unroll
      for (int n=0;n<4;n++) b[n] = *(const bf16x8*)&WcT[(wave*64 + n*16 + lr)*96 + k0 + lk];
      #pragma unroll
      for (int m=0;m<4;m++)
        #pragma unroll
        for (int n=0;n<4;n++)
          acc[m][n] = __builtin_amdgcn_mfma_f32_16x16x32_bf16(a[m], b[n], acc[m][n], 0,0,0);
    }
    __syncthreads();
    const int rbase = (lane>>4)*4;
    #pragma unroll
    for (int n=0;n<4;n++){
      const int c = wave*64 + n*16 + lr;
      const int ip = (c < 128) ? (2*c) : (2*(c-128)+1);
      #pragma unroll
      for (int m=0;m<4;m++)
        #pragma unroll
        for (int r=0;r<4;r++)
          kvs[(m*16 + rbase + r)*LDKV + ip] = f2bf(acc[m][n][r]);
    }
    __syncthreads();
    #pragma unroll
    for (int pass=0; pass<8; ++pass){
      const int idx = pass*256 + tid;
      const int row = idx>>5, seg = idx&31;
      const int nloc = row>>5, k = row&31;
      const uint vm = nloc ? vm1 : vm0;
      if ((vm>>k)&1u){
        const int slot = __popc(vm & ((1u<<k)-1));
        const uint4 v = *(const uint4*)&kvs[row*LDKV + seg*8];
        kvout[((size_t)(node0+nloc)*KK + slot)*32 + seg] = v;
      }
    }
  }
}

// ---------- attention: 1 wave/node, 2 j-cols/lane (uint2 loads), chunked online softmax ----------
__global__ __launch_bounds__(256) void k_attn6(
    const float* __restrict__ Qf, const uint2* __restrict__ KVu2, const uint2* __restrict__ kvaddC2,
    const int* __restrict__ nbrC, const int* __restrict__ cntb,
    const float* __restrict__ XN, const float* __restrict__ g2, const float* __restrict__ b2,
    float* __restrict__ H2, ushort* __restrict__ hnb){
  __shared__ int nbr_sh[4][KK];
  const int tid = threadIdx.x, node0 = blockIdx.x*4;
  if (tid < 128) nbr_sh[tid>>5][tid&31] = nbrC[(node0 + (tid>>5))*KK + (tid&31)];
  __syncthreads();
  const int wv = tid>>6, l = tid&63;
  const int node = node0 + wv;
  const int cnt = cntb[node];                 // wave-uniform
  const float2 q2 = *(const float2*)&Qf[(size_t)node*HH + 2*l];
  const float q0s = q2.x * ATTN_NORM, q1s = q2.y * ATTN_NORM;
  const uint2* karow = kvaddC2 + (size_t)node*KK*64 + l;
  float m_ = -3.0e38f, sume = 0.f, a0 = 0.f, a1 = 0.f;
  const int cc = (cnt + 7) >> 3;
  for (int ch=0; ch<cc; ++ch){
    const int base = ch*8;
    uint2 ka[8], kb[8];
    #pragma unroll
    for (int i=0;i<8;i++){
      int slot = base + i; slot = (slot < cnt) ? slot : (cnt-1);   // tail clamps to cached row
      ka[i] = karow[(size_t)slot*64];
      kb[i] = KVu2[(size_t)nbr_sh[wv][slot]*64 + l];
    }
    float s[8];
    #pragma unroll
    for (int i=0;i<8;i++){
      float p = q0s * (bf2f((ushort)(kb[i].x&0xffff)) + bf2f((ushort)(ka[i].x&0xffff)))
              + q1s * (bf2f((ushort)(kb[i].y&0xffff)) + bf2f((ushort)(ka[i].y&0xffff)));
      p += __shfl_xor(p, 4, 8);
      p += __shfl_xor(p, 2, 8);
      p += __shfl_xor(p, 1, 8);
      s[i] = (base + i < cnt) ? p : -1e30f;
    }
    float cm = s[0];
    #pragma unroll
    for (int i=1;i<8;i++) cm = fmaxf(cm, s[i]);
    const float mn = fmaxf(m_, cm);
    const float sc = __expf(m_ - mn);
    sume *= sc; a0 *= sc; a1 *= sc;
    #pragma unroll
    for (int i=0;i<8;i++){
      const float e = __expf(s[i] - mn);
      sume += e;
      a0 = fmaf(e, bf2f((ushort)(kb[i].x>>16)) + bf2f((ushort)(ka[i].x>>16)), a0);
      a1 = fmaf(e, bf2f((ushort)(kb[i].y>>16)) + bf2f((ushort)(ka[i].y>>16)), a1);
    }
    m_ = mn;
  }
  const float inv = (cnt > 0) ? (1.f / sume) : 0.f;   // zero-valid nodes -> 0 (has gate)
  const float2 xn2 = *(const float2*)&XN[(size_t)node*HH + 2*l];
  const float h0 = a0*inv + xn2.x;
  const float h1 = a1*inv + xn2.y;
  *(float2*)&H2[(size_t)node*HH + 2*l] = make_float2(h0, h1);
  const float mean = wavesum64(h0 + h1) * (1.f/HH);
  const float d0 = h0 - mean, d1 = h1 - mean;
  const float var = wavesum64(d0*d0 + d1*d1) * (1.f/HH);
  const float rstd = rsqrtf(var + LN_EPS);
  const float2 gv = *(const float2*)&g2[2*l];
  const float2 bv = *(const float2*)&b2[2*l];
  ushort2 hn;
  hn.x = f2bf(d0*rstd*gv.x + bv.x);
  hn.y = f2bf(d1*rstd*gv.y + bv.y);
  *(ushort2*)&hnb[(size_t)node*HH + 2*l] = hn;
}

// ---------- FFN via 2 MFMA GEMMs.
// LAST=0: fuse next layer's LN + kqv GEMM (hout stays on-chip).
// LAST=1: fuse out = h@Wo+bo.
#define LDA2 264   // 256+8 pad
template<int LAST>
__global__ __launch_bounds__(256) void k_ffn_mfma(const ushort* __restrict__ xnb, const ushort* __restrict__ hnb,
    const float* __restrict__ H2, const ushort* __restrict__ W1T, const float* __restrict__ bl1,
    const ushort* __restrict__ W2T, const float* __restrict__ bl2,
    const ushort* __restrict__ WoT, const float* __restrict__ bo, float* __restrict__ OUT,
    const ushort* __restrict__ WkqvT, const float* __restrict__ g1, const float* __restrict__ b1,
    const float* __restrict__ tqq, float* __restrict__ XN, ushort* __restrict__ xnbO,
    float* __restrict__ Qf, ushort* __restrict__ KVb){
  __shared__ ushort As[16*LDA2];
  __shared__ ushort Ms[16*LDA1];
  const int tid = threadIdx.x, n0 = blockIdx.x*16;
  {
    const int row = tid>>4, c8 = (tid&15)*8;
    *(uint4*)&As[row*LDA2 + c8]       = *(const uint4*)&xnb[(size_t)(n0+row)*HH + c8];
    *(uint4*)&As[row*LDA2 + 128 + c8] = *(const uint4*)&hnb[(size_t)(n0+row)*HH + c8];
  }
  __syncthreads();
  const int w = tid>>6, lane = tid&63;
  const int lr = lane&15, lk8 = (lane>>4)*8, rbase = (lane>>4)*4;
  {
    bf16x8 a[8];
    #pragma unroll
    for (int kk=0;kk<8;kk++) a[kk] = *(const bf16x8*)&As[lr*LDA2 + kk*32 + lk8];
    f32x4 acc[2];
    #pragma unroll
    for (int nt=0;nt<2;nt++) acc[nt] = (f32x4){0.f,0.f,0.f,0.f};
    #pragma unroll
    for (int nt=0;nt<2;nt++){
      const int n = w*2 + nt;
      #pragma unroll
      for (int kk=0;kk<8;kk++){
        bf16x8 b = *(const bf16x8*)&W1T[(n*16+lr)*256 + kk*32 + lk8];
        acc[nt] = __builtin_amdgcn_mfma_f32_16x16x32_bf16(a[kk], b, acc[nt],0,0,0);
      }
    }
    #pragma unroll
    for (int nt=0;nt<2;nt++){
      const int c = (w*2+nt)*16 + lr;
      const float bj = bl1[c];
      #pragma unroll
      for (int r=0;r<4;r++)
        Ms[(rbase+r)*LDA1 + c] = f2bf(fmaxf(acc[nt][r] + bj, 0.f));
    }
  }
  __syncthreads();
  {
    bf16x8 a[4];
    #pragma unroll
    for (int kk=0;kk<4;kk++) a[kk] = *(const bf16x8*)&Ms[lr*LDA1 + kk*32 + lk8];
    f32x4 acc[2];
    #pragma unroll
    for (int nt=0;nt<2;nt++) acc[nt] = (f32x4){0.f,0.f,0.f,0.f};
    #pragma unroll
    for (int nt=0;nt<2;nt++){
      const int n = w*2 + nt;
      #pragma unroll
      for (int kk=0;kk<4;kk++){
        bf16x8 b = *(const bf16x8*)&W2T[(n*16+lr)*HH + kk*32 + lk8];
        acc[nt] = __builtin_amdgcn_mfma_f32_16x16x32_bf16(a[kk], b, acc[nt],0,0,0);
      }
    }
    #pragma unroll
    for (int nt=0;nt<2;nt++){
      const int c = (w*2+nt)*16 + lr;
      const float bj = bl2[c];
      #pragma unroll
      for (int r=0;r<4;r++){
        const size_t node = n0 + rbase + r;
        const float hout = acc[nt][r] + bj + H2[node*HH + c];
        if (LAST){
          ((ushort*)As)[(rbase+r)*LDA1 + c] = f2bf(hout);   // bf16 h for out GEMM
        } else {
          ((float*)As)[(rbase+r)*LDH + c] = hout;           // fp32 h for fused LN
        }
      }
    }
  }
  __syncthreads();
  if (LAST){
    // out = h @ WoT + bo
    bf16x8 a[4];
    #pragma unroll
    for (int kk=0;kk<4;kk++) a[kk] = *(const bf16x8*)&((ushort*)As)[lr*LDA1 + kk*32 + lk8];
    f32x4 acc = (f32x4){0.f,0.f,0.f,0.f};
    #pragma unroll
    for (int kk=0;kk<4;kk++){
      bf16x8 b = *(const bf16x8*)&WoT[(w*16+lr)*HH + kk*32 + lk8];
      acc = __builtin_amdgcn_mfma_f32_16x16x32_bf16(a[kk], b, acc,0,0,0);
    }
    const int c = w*16 + lr;
    const float bj = bo[c];
    #pragma unroll
    for (int r=0;r<4;r++)
      OUT[(size_t)(n0 + rbase + r)*OUTF + c] = acc[r] + bj;
  } else {
    // fused next-layer LN -> Ms(bf16) + XN + xnbO, then kqv GEMM -> Qf/KVb
    const float* Hs = (const float*)As;
    const int grp = tid>>5, gl = tid&31;
    {
      const float4 gv = *(const float4*)&g1[gl*4];
      const float4 bv = *(const float4*)&b1[gl*4];
      #pragma unroll
      for (int rr=0; rr<2; ++rr){
        const int row = grp + rr*8;
        const int node = n0 + row;
        float4 hv = *(const float4*)&Hs[row*LDH + gl*4];
        float s = hv.x+hv.y+hv.z+hv.w;
        s = groupsum32(s);
        const float mean = s*(1.f/HH);
        const float dx=hv.x-mean, dy=hv.y-mean, dz=hv.z-mean, dw=hv.w-mean;
        float vs = dx*dx+dy*dy+dz*dz+dw*dw;
        vs = groupsum32(vs);
        const float rstd = rsqrtf(vs*(1.f/HH)+LN_EPS);
        const float x0=dx*rstd*gv.x+bv.x, x1=dy*rstd*gv.y+bv.y, x2=dz*rstd*gv.z+bv.z, x3=dw*rstd*gv.w+bv.w;
        ushort4 pk = make_ushort4(f2bf(x0), f2bf(x1), f2bf(x2), f2bf(x3));
        *(ushort4*)&Ms[row*LDA1 + gl*4] = pk;
        *(float4*)&XN[(size_t)node*HH + gl*4] = make_float4(x0,x1,x2,x3);
        *(ushort4*)&xnbO[(size_t)node*HH + gl*4] = pk;
      }
    }
    __syncthreads();
    bf16x8 a[4];
    #pragma unroll
    for (int kk=0;kk<4;kk++) a[kk] = *(const bf16x8*)&Ms[lr*LDA1 + kk*32 + lk8];
    f32x4 acc[6];
    #pragma unroll
    for (int nt=0;nt<6;nt++) acc[nt] = (f32x4){0.f,0.f,0.f,0.f};
    #pragma unroll
    for (int nt=0;nt<6;nt++){
      const int n = w*6 + nt;
      #pragma unroll
      for (int kk=0;kk<4;kk++){
        bf16x8 b = *(const bf16x8*)&WkqvT[(n*16+lr)*HH + kk*32 + lk8];
        acc[nt] = __builtin_amdgcn_mfma_f32_16x16x32_bf16(a[kk], b, acc[nt],0,0,0);
      }
    }
    #pragma unroll
    for (int nt=0;nt<6;nt++){
      const int c = (w*6+nt)*16 + lr;
      #pragma unroll
      for (int r=0;r<4;r++){
        const int node = n0 + rbase + r;
        const float v = acc[nt][r];
        if (c < HH)           KVb[(size_t)node*256 + 2*c] = f2bf(v);
        else if (c < 2*HH)    Qf[(size_t)node*HH + (c-HH)] = v + tqq[(size_t)node*HH + (c-HH)];
        else                  KVb[(size_t)node*256 + 2*(c-2*HH) + 1] = f2bf(v);
      }
    }
  }
}

extern "C" void kernel_launch(void* const* d_in, const int* in_sizes, int n_in,
                              void* d_out, int out_size, void* d_ws, size_t ws_size,
                              hipStream_t stream){
  const float* x         = (const float*)d_in[0];
  const int*   neighbors = (const int*)  d_in[1];
  const float* times     = (const float*)d_in[2];
  const float* rels      = (const float*)d_in[3];
  const float* Wp        = (const float*)d_in[4];
  const float* bp        = (const float*)d_in[5];
  const float* Wkqv      = (const float*)d_in[6];
  const float* Wt        = (const float*)d_in[7];
  const float* bt        = (const float*)d_in[8];
  const float* Wtime     = (const float*)d_in[9];
  const float* Wedge     = (const float*)d_in[10];
  const float* g1        = (const float*)d_in[11];
  const float* b1n       = (const float*)d_in[12];
  const float* g2        = (const float*)d_in[13];
  const float* b2n       = (const float*)d_in[14];
  const float* W1        = (const float*)d_in[15];
  const float* bl1       = (const float*)d_in[16];
  const float* W2        = (const float*)d_in[17];
  const float* bl2       = (const float*)d_in[18];
  const float* Wo        = (const float*)d_in[19];
  const float* bo        = (const float*)d_in[20];
  float* out = (float*)d_out;

  char* ws = (char*)d_ws;
  size_t off = 0;
  auto carve = [&](size_t bytes)->char*{
    char* p = ws + off; off = (off + bytes + 255) & ~(size_t)255; return p;
  };
  float* hA    = (float*)carve((size_t)NN*HH*4);
  float* xn    = (float*)carve((size_t)NN*HH*4);
  float* h2    = (float*)carve((size_t)NN*HH*4);
  float* tqq   = (float*)carve((size_t)NN*HH*4);
  float* Qfp   = (float*)carve((size_t)NN*HH*4);
  float* tmaxb = (float*)carve((size_t)NN*4);
  int*   cntb  = (int*)carve((size_t)NN*4);
  uint*  vmaskb= (uint*)carve((size_t)NN*4);
  int*   nbrC  = (int*)carve((size_t)(NN+4)*KK*4);
  ushort* KVb  = (ushort*)carve((size_t)NN*256*2);
  ushort* xnb  = (ushort*)carve((size_t)NN*HH*2);
  ushort* hnb  = (ushort*)carve((size_t)NN*HH*2);
  ushort* WcTg = (ushort*)carve((size_t)256*96*2);
  ushort* WpT  = (ushort*)carve((size_t)16384*2);
  ushort* WkqvT= (ushort*)carve((size_t)49152*2);
  ushort* W1T  = (ushort*)carve((size_t)32768*2);
  ushort* W2T  = (ushort*)carve((size_t)16384*2);
  ushort* WoT  = (ushort*)carve((size_t)8192*2);
  uint*   kvaddC = (uint*)carve((size_t)NN*KK*256*2);   // compacted interleaved (k,v) bf16 pairs
  (void)ws_size;

  k_prep_wT<<<576, 256, 0, stream>>>(Wp, Wkqv, W1, W2, Wo, Wtime, Wedge,
                                     WpT, WkqvT, W1T, W2T, WoT, WcTg);
  // merged: proj [0,625) | 2-node prep_node [625,5625)
  k_node_proj<<<NN/16 + NN/2, 256, 0, stream>>>(x, WpT, bp, hA,
                                                times, neighbors, Wt, bt, Wtime,
                                                tqq, tmaxb, cntb, vmaskb, nbrC);
  // merged: prep_kv4 [0,5000) | layer-0 ln_kqv [5000,5625)
  k_kv0_ln0<<<NN/2 + NN/16, 256, 0, stream>>>(times, rels, tmaxb, Wt, bt, WcTg, vmaskb,
                                              (uint4*)kvaddC,
                                              hA, WkqvT, g1, b1n, tqq, xn, xnb, Qfp, KVb);
  // layer 0: attn, then ffn fused with layer-1 LN+kqv
  k_attn6<<<NN/4, 256, 0, stream>>>(Qfp, (const uint2*)KVb, (const uint2*)kvaddC, nbrC, cntb,
                                    xn, g2, b2n, h2, hnb);
  k_ffn_mfma<0><<<NN/16, 256, 0, stream>>>(xnb, hnb, h2, W1T, bl1, W2T, bl2,
                                           WoT, bo, out,
                                           WkqvT, g1, b1n, tqq, xn, xnb, Qfp, KVb);
  // layer 1: attn, then ffn fused with out
  k_attn6<<<NN/4, 256, 0, stream>>>(Qfp, (const uint2*)KVb, (const uint2*)kvaddC, nbrC, cntb,
                                    xn, g2, b2n, h2, hnb);
  k_ffn_mfma<1><<<NN/16, 256, 0, stream>>>(xnb, hnb, h2, W1T, bl1, W2T, bl2,
                                           WoT, bo, out,
                                           WkqvT, g1, b1n, tqq, xn, xnb, Qfp, KVb);
}

// Round 20
// 158.924 us; speedup vs baseline: 1.0139x; 1.0139x over previous
//
#include <hip/hip_runtime.h>
#include <hip/hip_bf16.h>

#define NN 10000
#define KK 32
#define HH 128
#define TFH 32      // T_F/2
#define RFE 32
#define OUTF 64
#define START_T 0.25f
#define END_T 0.75f
#define ATTN_NORM 0.25f
#define T_NORM 0.17677669529663687f   // sqrt(1/32)
#define LN_EPS 1e-5f
#define MT 64

typedef __attribute__((ext_vector_type(4))) float f32x4;
typedef __attribute__((ext_vector_type(8))) short bf16x8;

__device__ __forceinline__ ushort f2bf(float x){
  __hip_bfloat16 b = __float2bfloat16(x);
  return *(ushort*)&b;
}
__device__ __forceinline__ float bf2f(ushort u){
  __hip_bfloat16 b = *(__hip_bfloat16*)&u;
  return __bfloat162float(b);
}

__device__ __forceinline__ float groupsum32(float v){
  v += __shfl_xor(v, 16, 32);
  v += __shfl_xor(v, 8, 32);
  v += __shfl_xor(v, 4, 32);
  v += __shfl_xor(v, 2, 32);
  v += __shfl_xor(v, 1, 32);
  return v;
}

__device__ __forceinline__ float wavesum64(float v){
  v += __shfl_xor(v, 32, 64);
  v += __shfl_xor(v, 16, 64);
  v += __shfl_xor(v, 8, 64);
  v += __shfl_xor(v, 4, 64);
  v += __shfl_xor(v, 2, 64);
  v += __shfl_xor(v, 1, 64);
  return v;
}

// ---------- one-time weight transposes to bf16 (all weights incl. WcT) ----------
__global__ __launch_bounds__(256) void k_prep_wT(const float* __restrict__ Wp, const float* __restrict__ Wkqv,
    const float* __restrict__ W1, const float* __restrict__ W2, const float* __restrict__ Wo,
    const float* __restrict__ Wtime, const float* __restrict__ Wedge,
    ushort* __restrict__ WpT, ushort* __restrict__ WkqvT, ushort* __restrict__ W1T,
    ushort* __restrict__ W2T, ushort* __restrict__ WoT, ushort* __restrict__ WcT){
  int id = blockIdx.x*256 + threadIdx.x;
  if (id < 16384){ int n=id>>7, k=id&127; WpT[id]=f2bf(Wp[k*HH+n]); return; }
  id -= 16384;
  if (id < 49152){ int n=id>>7, k=id&127; WkqvT[id]=f2bf(Wkqv[k*384+n]); return; }
  id -= 49152;
  if (id < 32768){ int n=id>>8, k=id&255; W1T[id]=f2bf(W1[k*HH+n]); return; }
  id -= 32768;
  if (id < 16384){ int n=id>>7, k=id&127; W2T[id]=f2bf(W2[k*HH+n]); return; }
  id -= 16384;
  if (id < 8192){ int n=id>>7, k=id&127; WoT[id]=f2bf(Wo[k*OUTF+n]); return; }
  id -= 8192;
  if (id < 24576){
    const int c = id/96, r = id%96;
    const int cc = (c < 128) ? c : (c + 128);
    const float v = (r < 64) ? Wtime[r*384 + cc] : Wedge[(r-64)*384 + cc];
    WcT[c*96 + r] = f2bf(v);
  }
}

#define LDA1 136   // 128+8 pad (ushorts)
#define LDA 104    // 96+8 pad (ushorts)
#define LDKV 264   // 256+8 pad (ushorts)
#define LDH 132    // 128+4 pad (floats)

// ---------- merged: proj (blocks [0,625)) | 2-node prep_node (blocks [625,5625)) ----------
__global__ __launch_bounds__(256) void k_node_proj(
    const float* __restrict__ X, const ushort* __restrict__ WpT, const float* __restrict__ bp,
    float* __restrict__ Y,
    const float* __restrict__ times, const int* __restrict__ nbrs,
    const float* __restrict__ Wt, const float* __restrict__ bt, const float* __restrict__ Wtime,
    float* __restrict__ tqq, float* __restrict__ tmaxb,
    int* __restrict__ cntb, uint* __restrict__ vmaskb, int* __restrict__ nbrC){
  __shared__ ushort As[16*LDA1];
  __shared__ float temb2[2][2*TFH];
  __shared__ float tmax_sh[2];
  const int tid = threadIdx.x;
  if (blockIdx.x < NN/16){
    const int n0 = blockIdx.x*16;
    #pragma unroll
    for (int p=0;p<2;++p){
      const int idx = tid + p*256;
      const int row = idx>>5, c4 = (idx&31)*4;
      const float4 v = *(const float4*)&X[(size_t)(n0+row)*HH + c4];
      *(ushort4*)&As[row*LDA1 + c4] = make_ushort4(f2bf(v.x), f2bf(v.y), f2bf(v.z), f2bf(v.w));
    }
    __syncthreads();
    const int w = tid>>6, lane = tid&63;
    const int lr = lane&15, lk8 = (lane>>4)*8, rbase = (lane>>4)*4;
    bf16x8 a[4];
    #pragma unroll
    for (int kk=0;kk<4;kk++) a[kk] = *(const bf16x8*)&As[lr*LDA1 + kk*32 + lk8];
    f32x4 acc[2];
    #pragma unroll
    for (int nt=0;nt<2;nt++) acc[nt] = (f32x4){0.f,0.f,0.f,0.f};
    #pragma unroll
    for (int nt=0;nt<2;nt++){
      const int n = w*2 + nt;
      #pragma unroll
      for (int kk=0;kk<4;kk++){
        bf16x8 b = *(const bf16x8*)&WpT[(n*16+lr)*HH + kk*32 + lk8];
        acc[nt] = __builtin_amdgcn_mfma_f32_16x16x32_bf16(a[kk], b, acc[nt],0,0,0);
      }
    }
    #pragma unroll
    for (int nt=0;nt<2;nt++){
      const int c = (w*2+nt)*16 + lr;
      const float bj = bp[c];
      #pragma unroll
      for (int r=0;r<4;r++)
        Y[(size_t)(n0 + rbase + r)*HH + c] = fmaxf(acc[nt][r] + bj, 0.f);
    }
  } else {
    const int node0 = (blockIdx.x - NN/16)*2;
    if (tid < MT){
      const int i = tid>>5, k = tid&31;
      const int node = node0 + i;
      const float t = times[node*KK + k];
      const bool valid = (t >= START_T) && (t < END_T);
      float val = valid ? t : START_T;
      #pragma unroll
      for (int off=16; off; off>>=1) val = fmaxf(val, __shfl_xor(val, off, 32));
      const unsigned long long bal = __ballot(valid);
      const uint vm = (uint)(bal >> (i*32));
      if (valid){
        const int slot = __popc(vm & ((1u<<k)-1));
        nbrC[node*KK + slot] = nbrs[node*KK + k];
      }
      if (k==0){ cntb[node] = __popc(vm); vmaskb[node] = vm; tmaxb[node] = val; tmax_sh[i] = val; }
    }
    __syncthreads();
    if (tid < MT){
      const int i = tid>>5, f = tid&31;
      const float hh = fmaf(tmax_sh[i] - START_T, Wt[f], bt[f]);
      temb2[i][2*f]   = __sinf(hh)*T_NORM;
      temb2[i][2*f+1] = __cosf(hh)*T_NORM;
    }
    __syncthreads();
    {
      const int i = tid>>7, jj = tid&127;
      float acc = 0.f;
      #pragma unroll
      for (int f=0; f<2*TFH; f++) acc = fmaf(temb2[i][f], Wtime[f*384 + HH + jj], acc);
      tqq[(size_t)(node0+i)*HH + jj] = acc;
    }
  }
}

// ---------- merged: layer-0 ln_kqv (blocks [0,625)) | prep_kv4 (blocks [625,5625)) ----------
// prep branch: register-dt + early rels issue (R16).
__global__ __launch_bounds__(256) void k_kv0_ln0(
    const float* __restrict__ times, const float* __restrict__ rels, const float* __restrict__ tmaxb,
    const float* __restrict__ Wt, const float* __restrict__ bt, const ushort* __restrict__ WcT,
    const uint* __restrict__ vmaskb, uint4* __restrict__ kvout,
    const float* __restrict__ Hin, const ushort* __restrict__ WkqvT,
    const float* __restrict__ g1, const float* __restrict__ b1, const float* __restrict__ tqq,
    float* __restrict__ XN, ushort* __restrict__ xnb,
    float* __restrict__ Qf, ushort* __restrict__ KVb){
  __shared__ ushort smem[MT*LDKV];
  const int tid = threadIdx.x;
  if (blockIdx.x < NN/16){
    ushort* As = smem;
    const int n0 = blockIdx.x*16;
    const int grp = tid>>5, gl = tid&31;
    {
      const float4 gv = *(const float4*)&g1[gl*4];
      const float4 bv = *(const float4*)&b1[gl*4];
      #pragma unroll
      for (int rr=0; rr<2; ++rr){
        const int row = grp + rr*8;
        const int node = n0 + row;
        float4 hv = *(const float4*)&Hin[(size_t)node*HH + gl*4];
        float s = hv.x+hv.y+hv.z+hv.w;
        s = groupsum32(s);
        const float mean = s*(1.f/HH);
        const float dx=hv.x-mean, dy=hv.y-mean, dz=hv.z-mean, dw=hv.w-mean;
        float vs = dx*dx+dy*dy+dz*dz+dw*dw;
        vs = groupsum32(vs);
        const float rstd = rsqrtf(vs*(1.f/HH)+LN_EPS);
        const float x0=dx*rstd*gv.x+bv.x, x1=dy*rstd*gv.y+bv.y, x2=dz*rstd*gv.z+bv.z, x3=dw*rstd*gv.w+bv.w;
        ushort4 pk = make_ushort4(f2bf(x0), f2bf(x1), f2bf(x2), f2bf(x3));
        *(ushort4*)&As[row*LDA1 + gl*4] = pk;
        *(float4*)&XN[(size_t)node*HH + gl*4] = make_float4(x0,x1,x2,x3);
        *(ushort4*)&xnb[(size_t)node*HH + gl*4] = pk;
      }
    }
    __syncthreads();
    const int w = tid>>6, lane = tid&63;
    const int lr = lane&15, lk8 = (lane>>4)*8, rbase = (lane>>4)*4;
    bf16x8 a[4];
    #pragma unroll
    for (int kk=0;kk<4;kk++) a[kk] = *(const bf16x8*)&As[lr*LDA1 + kk*32 + lk8];
    f32x4 acc[6];
    #pragma unroll
    for (int nt=0;nt<6;nt++) acc[nt] = (f32x4){0.f,0.f,0.f,0.f};
    #pragma unroll
    for (int nt=0;nt<6;nt++){
      const int n = w*6 + nt;
      #pragma unroll
      for (int kk=0;kk<4;kk++){
        bf16x8 b = *(const bf16x8*)&WkqvT[(n*16+lr)*HH + kk*32 + lk8];
        acc[nt] = __builtin_amdgcn_mfma_f32_16x16x32_bf16(a[kk], b, acc[nt],0,0,0);
      }
    }
    #pragma unroll
    for (int nt=0;nt<6;nt++){
      const int c = (w*6+nt)*16 + lr;
      #pragma unroll
      for (int r=0;r<4;r++){
        const int node = n0 + rbase + r;
        const float v = acc[nt][r];
        if (c < HH)           KVb[(size_t)node*256 + 2*c] = f2bf(v);
        else if (c < 2*HH)    Qf[(size_t)node*HH + (c-HH)] = v + tqq[(size_t)node*HH + (c-HH)];
        else                  KVb[(size_t)node*256 + 2*(c-2*HH) + 1] = f2bf(v);
      }
    }
  } else {
    ushort* Fa = smem;
    ushort* kvs = smem;
    const int node0 = (blockIdx.x - NN/16)*2;
    // early independent loads: rels (HBM-latency hidden under sincos), tmax, vmask
    float4 rv[2];
    int relp[2], relseg[2];
    #pragma unroll
    for (int s0=0; s0<2; ++s0){
      const int i = tid + s0*256;
      relp[s0] = i>>3; relseg[s0] = i&7;
      rv[s0] = *(const float4*)&rels[((size_t)node0*KK + relp[s0])*RFE + relseg[s0]*4];
    }
    const float tmax0 = tmaxb[node0], tmax1 = tmaxb[node0+1];
    const uint vm0 = vmaskb[node0], vm1 = vmaskb[node0+1];
    // Fa sincos: f = tid&31 constant per thread; dt computed in registers (no dt_sh, no barrier)
    {
      const int f = tid&31;
      const float wtf = Wt[f], btf = bt[f];
      #pragma unroll
      for (int s0=0; s0<8; ++s0){
        const int p = (tid>>5) + 8*s0;
        const float tv = times[node0*KK + p];           // broadcast within 32-thread group
        const float dt = ((p < 32) ? tmax0 : tmax1) - tv;
        const float hh = fmaf(dt, wtf, btf);
        ushort2 pk;
        pk.x = f2bf(__sinf(hh)*T_NORM);
        pk.y = f2bf(__cosf(hh)*T_NORM);
        *(ushort2*)&Fa[p*LDA + 2*f] = pk;
      }
    }
    #pragma unroll
    for (int s0=0; s0<2; ++s0){
      ushort4 w2; w2.x=f2bf(rv[s0].x); w2.y=f2bf(rv[s0].y); w2.z=f2bf(rv[s0].z); w2.w=f2bf(rv[s0].w);
      *(ushort4*)&Fa[relp[s0]*LDA + 64 + relseg[s0]*4] = w2;
    }
    __syncthreads();
    const int wave = tid>>6, lane = tid&63;
    const int lr = lane&15, lk = (lane>>4)*8;
    f32x4 acc[4][4];
    #pragma unroll
    for (int m=0;m<4;m++)
      #pragma unroll
      for (int n=0;n<4;n++) acc[m][n] = (f32x4){0.f,0.f,0.f,0.f};
    #pragma unroll
    for (int kk=0; kk<3; ++kk){
      const int k0 = kk*32;
      bf16x8 a[4], b[4];
      #pragma unroll
      for (int m=0;m<4;m++) a[m] = *(const bf16x8*)&Fa[(m*16 + lr)*LDA + k0 + lk];
      #pragma unroll
      for (int n=0;n<4;n++) b[n] = *(const bf16x8*)&WcT[(wave*64 + n*16 + lr)*96 + k0 + lk];
      #pragma unroll
      for (int m=0;m<4;m++)
        #pragma unroll
        for (int n=0;n<4;n++)
          acc[m][n] = __builtin_amdgcn_mfma_f32_16x16x32_bf16(a[m], b[n], acc[m][n], 0,0,0);
    }
    __syncthreads();
    const int rbase = (lane>>4)*4;
    #pragma unroll
    for (int n=0;n<4;n++){
      const int c = wave*64 + n*16 + lr;
      const int ip = (c < 128) ? (2*c) : (2*(c-128)+1);
      #pragma unroll
      for (int m=0;m<4;m++)
        #pragma unroll
        for (int r=0;r<4;r++)
          kvs[(m*16 + rbase + r)*LDKV + ip] = f2bf(acc[m][n][r]);
    }
    __syncthreads();
    #pragma unroll
    for (int pass=0; pass<8; ++pass){
      const int idx = pass*256 + tid;
      const int row = idx>>5, seg = idx&31;
      const int nloc = row>>5, k = row&31;
      const uint vm = nloc ? vm1 : vm0;
      if ((vm>>k)&1u){
        const int slot = __popc(vm & ((1u<<k)-1));
        const uint4 v = *(const uint4*)&kvs[row*LDKV + seg*8];
        kvout[((size_t)(node0+nloc)*KK + slot)*32 + seg] = v;
      }
    }
  }
}

// ---------- attention: 1 wave/node, 2 j-cols/lane (uint2 loads), chunked online softmax ----------
__global__ __launch_bounds__(256) void k_attn6(
    const float* __restrict__ Qf, const uint2* __restrict__ KVu2, const uint2* __restrict__ kvaddC2,
    const int* __restrict__ nbrC, const int* __restrict__ cntb,
    const float* __restrict__ XN, const float* __restrict__ g2, const float* __restrict__ b2,
    float* __restrict__ H2, ushort* __restrict__ hnb){
  __shared__ int nbr_sh[4][KK];
  const int tid = threadIdx.x, node0 = blockIdx.x*4;
  if (tid < 128) nbr_sh[tid>>5][tid&31] = nbrC[(node0 + (tid>>5))*KK + (tid&31)];
  __syncthreads();
  const int wv = tid>>6, l = tid&63;
  const int node = node0 + wv;
  const int cnt = cntb[node];                 // wave-uniform
  const float2 q2 = *(const float2*)&Qf[(size_t)node*HH + 2*l];
  const float q0s = q2.x * ATTN_NORM, q1s = q2.y * ATTN_NORM;
  const uint2* karow = kvaddC2 + (size_t)node*KK*64 + l;
  float m_ = -3.0e38f, sume = 0.f, a0 = 0.f, a1 = 0.f;
  const int cc = (cnt + 7) >> 3;
  for (int ch=0; ch<cc; ++ch){
    const int base = ch*8;
    uint2 ka[8], kb[8];
    #pragma unroll
    for (int i=0;i<8;i++){
      int slot = base + i; slot = (slot < cnt) ? slot : (cnt-1);   // tail clamps to cached row
      ka[i] = karow[(size_t)slot*64];
      kb[i] = KVu2[(size_t)nbr_sh[wv][slot]*64 + l];
    }
    float s[8];
    #pragma unroll
    for (int i=0;i<8;i++){
      float p = q0s * (bf2f((ushort)(kb[i].x&0xffff)) + bf2f((ushort)(ka[i].x&0xffff)))
              + q1s * (bf2f((ushort)(kb[i].y&0xffff)) + bf2f((ushort)(ka[i].y&0xffff)));
      p += __shfl_xor(p, 4, 8);
      p += __shfl_xor(p, 2, 8);
      p += __shfl_xor(p, 1, 8);
      s[i] = (base + i < cnt) ? p : -1e30f;
    }
    float cm = s[0];
    #pragma unroll
    for (int i=1;i<8;i++) cm = fmaxf(cm, s[i]);
    const float mn = fmaxf(m_, cm);
    const float sc = __expf(m_ - mn);
    sume *= sc; a0 *= sc; a1 *= sc;
    #pragma unroll
    for (int i=0;i<8;i++){
      const float e = __expf(s[i] - mn);
      sume += e;
      a0 = fmaf(e, bf2f((ushort)(kb[i].x>>16)) + bf2f((ushort)(ka[i].x>>16)), a0);
      a1 = fmaf(e, bf2f((ushort)(kb[i].y>>16)) + bf2f((ushort)(ka[i].y>>16)), a1);
    }
    m_ = mn;
  }
  const float inv = (cnt > 0) ? (1.f / sume) : 0.f;   // zero-valid nodes -> 0 (has gate)
  const float2 xn2 = *(const float2*)&XN[(size_t)node*HH + 2*l];
  const float h0 = a0*inv + xn2.x;
  const float h1 = a1*inv + xn2.y;
  *(float2*)&H2[(size_t)node*HH + 2*l] = make_float2(h0, h1);
  const float mean = wavesum64(h0 + h1) * (1.f/HH);
  const float d0 = h0 - mean, d1 = h1 - mean;
  const float var = wavesum64(d0*d0 + d1*d1) * (1.f/HH);
  const float rstd = rsqrtf(var + LN_EPS);
  const float2 gv = *(const float2*)&g2[2*l];
  const float2 bv = *(const float2*)&b2[2*l];
  ushort2 hn;
  hn.x = f2bf(d0*rstd*gv.x + bv.x);
  hn.y = f2bf(d1*rstd*gv.y + bv.y);
  *(ushort2*)&hnb[(size_t)node*HH + 2*l] = hn;
}

// ---------- FFN via 2 MFMA GEMMs.
// LAST=0: fuse next layer's LN + kqv GEMM (hout stays on-chip).
// LAST=1: fuse out = h@Wo+bo.
#define LDA2 264   // 256+8 pad
template<int LAST>
__global__ __launch_bounds__(256) void k_ffn_mfma(const ushort* __restrict__ xnb, const ushort* __restrict__ hnb,
    const float* __restrict__ H2, const ushort* __restrict__ W1T, const float* __restrict__ bl1,
    const ushort* __restrict__ W2T, const float* __restrict__ bl2,
    const ushort* __restrict__ WoT, const float* __restrict__ bo, float* __restrict__ OUT,
    const ushort* __restrict__ WkqvT, const float* __restrict__ g1, const float* __restrict__ b1,
    const float* __restrict__ tqq, float* __restrict__ XN, ushort* __restrict__ xnbO,
    float* __restrict__ Qf, ushort* __restrict__ KVb){
  __shared__ ushort As[16*LDA2];
  __shared__ ushort Ms[16*LDA1];
  const int tid = threadIdx.x, n0 = blockIdx.x*16;
  {
    const int row = tid>>4, c8 = (tid&15)*8;
    *(uint4*)&As[row*LDA2 + c8]       = *(const uint4*)&xnb[(size_t)(n0+row)*HH + c8];
    *(uint4*)&As[row*LDA2 + 128 + c8] = *(const uint4*)&hnb[(size_t)(n0+row)*HH + c8];
  }
  __syncthreads();
  const int w = tid>>6, lane = tid&63;
  const int lr = lane&15, lk8 = (lane>>4)*8, rbase = (lane>>4)*4;
  {
    bf16x8 a[8];
    #pragma unroll
    for (int kk=0;kk<8;kk++) a[kk] = *(const bf16x8*)&As[lr*LDA2 + kk*32 + lk8];
    f32x4 acc[2];
    #pragma unroll
    for (int nt=0;nt<2;nt++) acc[nt] = (f32x4){0.f,0.f,0.f,0.f};
    #pragma unroll
    for (int nt=0;nt<2;nt++){
      const int n = w*2 + nt;
      #pragma unroll
      for (int kk=0;kk<8;kk++){
        bf16x8 b = *(const bf16x8*)&W1T[(n*16+lr)*256 + kk*32 + lk8];
        acc[nt] = __builtin_amdgcn_mfma_f32_16x16x32_bf16(a[kk], b, acc[nt],0,0,0);
      }
    }
    #pragma unroll
    for (int nt=0;nt<2;nt++){
      const int c = (w*2+nt)*16 + lr;
      const float bj = bl1[c];
      #pragma unroll
      for (int r=0;r<4;r++)
        Ms[(rbase+r)*LDA1 + c] = f2bf(fmaxf(acc[nt][r] + bj, 0.f));
    }
  }
  __syncthreads();
  {
    bf16x8 a[4];
    #pragma unroll
    for (int kk=0;kk<4;kk++) a[kk] = *(const bf16x8*)&Ms[lr*LDA1 + kk*32 + lk8];
    f32x4 acc[2];
    #pragma unroll
    for (int nt=0;nt<2;nt++) acc[nt] = (f32x4){0.f,0.f,0.f,0.f};
    #pragma unroll
    for (int nt=0;nt<2;nt++){
      const int n = w*2 + nt;
      #pragma unroll
      for (int kk=0;kk<4;kk++){
        bf16x8 b = *(const bf16x8*)&W2T[(n*16+lr)*HH + kk*32 + lk8];
        acc[nt] = __builtin_amdgcn_mfma_f32_16x16x32_bf16(a[kk], b, acc[nt],0,0,0);
      }
    }
    #pragma unroll
    for (int nt=0;nt<2;nt++){
      const int c = (w*2+nt)*16 + lr;
      const float bj = bl2[c];
      #pragma unroll
      for (int r=0;r<4;r++){
        const size_t node = n0 + rbase + r;
        const float hout = acc[nt][r] + bj + H2[node*HH + c];
        if (LAST){
          ((ushort*)As)[(rbase+r)*LDA1 + c] = f2bf(hout);   // bf16 h for out GEMM
        } else {
          ((float*)As)[(rbase+r)*LDH + c] = hout;           // fp32 h for fused LN
        }
      }
    }
  }
  __syncthreads();
  if (LAST){
    // out = h @ WoT + bo
    bf16x8 a[4];
    #pragma unroll
    for (int kk=0;kk<4;kk++) a[kk] = *(const bf16x8*)&((ushort*)As)[lr*LDA1 + kk*32 + lk8];
    f32x4 acc = (f32x4){0.f,0.f,0.f,0.f};
    #pragma unroll
    for (int kk=0;kk<4;kk++){
      bf16x8 b = *(const bf16x8*)&WoT[(w*16+lr)*HH + kk*32 + lk8];
      acc = __builtin_amdgcn_mfma_f32_16x16x32_bf16(a[kk], b, acc,0,0,0);
    }
    const int c = w*16 + lr;
    const float bj = bo[c];
    #pragma unroll
    for (int r=0;r<4;r++)
      OUT[(size_t)(n0 + rbase + r)*OUTF + c] = acc[r] + bj;
  } else {
    // fused next-layer LN -> Ms(bf16) + XN + xnbO, then kqv GEMM -> Qf/KVb
    const float* Hs = (const float*)As;
    const int grp = tid>>5, gl = tid&31;
    {
      const float4 gv = *(const float4*)&g1[gl*4];
      const float4 bv = *(const float4*)&b1[gl*4];
      #pragma unroll
      for (int rr=0; rr<2; ++rr){
        const int row = grp + rr*8;
        const int node = n0 + row;
        float4 hv = *(const float4*)&Hs[row*LDH + gl*4];
        float s = hv.x+hv.y+hv.z+hv.w;
        s = groupsum32(s);
        const float mean = s*(1.f/HH);
        const float dx=hv.x-mean, dy=hv.y-mean, dz=hv.z-mean, dw=hv.w-mean;
        float vs = dx*dx+dy*dy+dz*dz+dw*dw;
        vs = groupsum32(vs);
        const float rstd = rsqrtf(vs*(1.f/HH)+LN_EPS);
        const float x0=dx*rstd*gv.x+bv.x, x1=dy*rstd*gv.y+bv.y, x2=dz*rstd*gv.z+bv.z, x3=dw*rstd*gv.w+bv.w;
        ushort4 pk = make_ushort4(f2bf(x0), f2bf(x1), f2bf(x2), f2bf(x3));
        *(ushort4*)&Ms[row*LDA1 + gl*4] = pk;
        *(float4*)&XN[(size_t)node*HH + gl*4] = make_float4(x0,x1,x2,x3);
        *(ushort4*)&xnbO[(size_t)node*HH + gl*4] = pk;
      }
    }
    __syncthreads();
    bf16x8 a[4];
    #pragma unroll
    for (int kk=0;kk<4;kk++) a[kk] = *(const bf16x8*)&Ms[lr*LDA1 + kk*32 + lk8];
    f32x4 acc[6];
    #pragma unroll
    for (int nt=0;nt<6;nt++) acc[nt] = (f32x4){0.f,0.f,0.f,0.f};
    #pragma unroll
    for (int nt=0;nt<6;nt++){
      const int n = w*6 + nt;
      #pragma unroll
      for (int kk=0;kk<4;kk++){
        bf16x8 b = *(const bf16x8*)&WkqvT[(n*16+lr)*HH + kk*32 + lk8];
        acc[nt] = __builtin_amdgcn_mfma_f32_16x16x32_bf16(a[kk], b, acc[nt],0,0,0);
      }
    }
    #pragma unroll
    for (int nt=0;nt<6;nt++){
      const int c = (w*6+nt)*16 + lr;
      #pragma unroll
      for (int r=0;r<4;r++){
        const int node = n0 + rbase + r;
        const float v = acc[nt][r];
        if (c < HH)           KVb[(size_t)node*256 + 2*c] = f2bf(v);
        else if (c < 2*HH)    Qf[(size_t)node*HH + (c-HH)] = v + tqq[(size_t)node*HH + (c-HH)];
        else                  KVb[(size_t)node*256 + 2*(c-2*HH) + 1] = f2bf(v);
      }
    }
  }
}

extern "C" void kernel_launch(void* const* d_in, const int* in_sizes, int n_in,
                              void* d_out, int out_size, void* d_ws, size_t ws_size,
                              hipStream_t stream){
  const float* x         = (const float*)d_in[0];
  const int*   neighbors = (const int*)  d_in[1];
  const float* times     = (const float*)d_in[2];
  const float* rels      = (const float*)d_in[3];
  const float* Wp        = (const float*)d_in[4];
  const float* bp        = (const float*)d_in[5];
  const float* Wkqv      = (const float*)d_in[6];
  const float* Wt        = (const float*)d_in[7];
  const float* bt        = (const float*)d_in[8];
  const float* Wtime     = (const float*)d_in[9];
  const float* Wedge     = (const float*)d_in[10];
  const float* g1        = (const float*)d_in[11];
  const float* b1n       = (const float*)d_in[12];
  const float* g2        = (const float*)d_in[13];
  const float* b2n       = (const float*)d_in[14];
  const float* W1        = (const float*)d_in[15];
  const float* bl1       = (const float*)d_in[16];
  const float* W2        = (const float*)d_in[17];
  const float* bl2       = (const float*)d_in[18];
  const float* Wo        = (const float*)d_in[19];
  const float* bo        = (const float*)d_in[20];
  float* out = (float*)d_out;

  char* ws = (char*)d_ws;
  size_t off = 0;
  auto carve = [&](size_t bytes)->char*{
    char* p = ws + off; off = (off + bytes + 255) & ~(size_t)255; return p;
  };
  float* hA    = (float*)carve((size_t)NN*HH*4);
  float* xn    = (float*)carve((size_t)NN*HH*4);
  float* h2    = (float*)carve((size_t)NN*HH*4);
  float* tqq   = (float*)carve((size_t)NN*HH*4);
  float* Qfp   = (float*)carve((size_t)NN*HH*4);
  float* tmaxb = (float*)carve((size_t)NN*4);
  int*   cntb  = (int*)carve((size_t)NN*4);
  uint*  vmaskb= (uint*)carve((size_t)NN*4);
  int*   nbrC  = (int*)carve((size_t)(NN+4)*KK*4);
  ushort* KVb  = (ushort*)carve((size_t)NN*256*2);
  ushort* xnb  = (ushort*)carve((size_t)NN*HH*2);
  ushort* hnb  = (ushort*)carve((size_t)NN*HH*2);
  ushort* WcTg = (ushort*)carve((size_t)256*96*2);
  ushort* WpT  = (ushort*)carve((size_t)16384*2);
  ushort* WkqvT= (ushort*)carve((size_t)49152*2);
  ushort* W1T  = (ushort*)carve((size_t)32768*2);
  ushort* W2T  = (ushort*)carve((size_t)16384*2);
  ushort* WoT  = (ushort*)carve((size_t)8192*2);
  uint*   kvaddC = (uint*)carve((size_t)NN*KK*256*2);   // compacted interleaved (k,v) bf16 pairs
  (void)ws_size;

  k_prep_wT<<<576, 256, 0, stream>>>(Wp, Wkqv, W1, W2, Wo, Wtime, Wedge,
                                     WpT, WkqvT, W1T, W2T, WoT, WcTg);
  // merged: proj [0,625) | 2-node prep_node [625,5625)
  k_node_proj<<<NN/16 + NN/2, 256, 0, stream>>>(x, WpT, bp, hA,
                                                times, neighbors, Wt, bt, Wtime,
                                                tqq, tmaxb, cntb, vmaskb, nbrC);
  // merged: layer-0 ln_kqv [0,625) | prep_kv4 [625,5625)
  k_kv0_ln0<<<NN/16 + NN/2, 256, 0, stream>>>(times, rels, tmaxb, Wt, bt, WcTg, vmaskb,
                                              (uint4*)kvaddC,
                                              hA, WkqvT, g1, b1n, tqq, xn, xnb, Qfp, KVb);
  // layer 0: attn, then ffn fused with layer-1 LN+kqv
  k_attn6<<<NN/4, 256, 0, stream>>>(Qfp, (const uint2*)KVb, (const uint2*)kvaddC, nbrC, cntb,
                                    xn, g2, b2n, h2, hnb);
  k_ffn_mfma<0><<<NN/16, 256, 0, stream>>>(xnb, hnb, h2, W1T, bl1, W2T, bl2,
                                           WoT, bo, out,
                                           WkqvT, g1, b1n, tqq, xn, xnb, Qfp, KVb);
  // layer 1: attn, then ffn fused with out
  k_attn6<<<NN/4, 256, 0, stream>>>(Qfp, (const uint2*)KVb, (const uint2*)kvaddC, nbrC, cntb,
                                    xn, g2, b2n, h2, hnb);
  k_ffn_mfma<1><<<NN/16, 256, 0, stream>>>(xnb, hnb, h2, W1T, bl1, W2T, bl2,
                                           WoT, bo, out,
                                           WkqvT, g1, b1n, tqq, xn, xnb, Qfp, KVb);
}